// Round 2
// baseline (58.319 us; speedup 1.0000x reference)
//
#include <hip/hip_runtime.h>
#include <hip/hip_cooperative_groups.h>
#include <cstdint>
#include <cstddef>

namespace cg = cooperative_groups;

#define BB 64
#define CC 1024
#define GRID 64
#define BLK 256

// Single cooperative kernel.
// Phase 1: parent[i] = max{ j < i : R[i,j] != 0 } (ancestor chains are strictly
//          decreasing, so the largest proper ancestor is the parent). Spread
//          across all 256 waves of the grid.
// Phase 2: one block per batch b: x = sigmoid(h); probs = x (argmax of paths is
//          provably root 0; R[:,0]==1); mcm via ancestor-chain max walk; pv via
//          ancestor-chain scatter with deterministic integer atomicMin on LDS;
//          per-batch partial BCE sum.
// Phase 3: block 0 deterministically reduces the 64 partials.
__global__ __launch_bounds__(BLK) void k_fused(const float* __restrict__ H,
                                               const float* __restrict__ Y,
                                               const float* __restrict__ R,
                                               float* __restrict__ out,
                                               int* __restrict__ parent,
                                               float* __restrict__ partial) {
    cg::grid_group grid = cg::this_grid();
    const int b = blockIdx.x;
    const int t = threadIdx.x;
    const int lane = t & 63;
    const int gwave = (b << 2) | (t >> 6);  // 0..255

    // ---------------- Phase 1: parent extraction ----------------
    for (int i = gwave; i < CC; i += GRID * (BLK / 64)) {
        const float* row = R + (size_t)i * CC;
        int best = -1;
        for (int j = lane; j < i; j += 64)
            if (row[j] != 0.0f) best = j;  // j increases per lane -> last hit is max
        #pragma unroll
        for (int off = 32; off > 0; off >>= 1) {
            int o = __shfl_down(best, off);
            best = best > o ? best : o;
        }
        if (lane == 0) parent[i] = best < 0 ? 0 : best;
    }
    __threadfence();
    grid.sync();

    // ---------------- Phase 2: per-batch main (b = 0..63) ----------------
    __shared__ float xs[CC];
    __shared__ int   pvb[CC];
    __shared__ int   par[CC];
    __shared__ float redsum[4];

    const float* h = H + (size_t)b * CC;
    const float* y = Y + (size_t)b * CC;

    float4 h4 = reinterpret_cast<const float4*>(h)[t];
    float xv[4];
    xv[0] = 1.0f / (1.0f + expf(-h4.x));
    xv[1] = 1.0f / (1.0f + expf(-h4.y));
    xv[2] = 1.0f / (1.0f + expf(-h4.z));
    xv[3] = 1.0f / (1.0f + expf(-h4.w));

    int4 p4 = reinterpret_cast<const int4*>(parent)[t];
    const int base = 4 * t;
    par[base + 0] = p4.x;
    par[base + 1] = p4.y;
    par[base + 2] = p4.z;
    par[base + 3] = p4.w;
    #pragma unroll
    for (int c = 0; c < 4; ++c) {
        xs[base + c]  = xv[c];
        pvb[base + c] = __float_as_int(xv[c]);
    }
    __syncthreads();

    // pv for root = min over ALL x (block reduction; avoids 1024-way atomic
    // contention on pvb[0]).
    float lm = fminf(fminf(xv[0], xv[1]), fminf(xv[2], xv[3]));
    #pragma unroll
    for (int off = 32; off > 0; off >>= 1) lm = fminf(lm, __shfl_down(lm, off));
    if ((t & 63) == 0) atomicMin(&pvb[0], __float_as_int(lm));

    // Ancestor-chain walks: mcm (register max) + pv scatter (LDS atomicMin,
    // order-independent -> deterministic).
    float mcm[4];
    #pragma unroll
    for (int c = 0; c < 4; ++c) {
        const int i = base + c;
        float m = xv[c];
        if (i != 0) {
            const int xib = __float_as_int(xv[c]);
            int a = par[i];
            while (a != 0) {
                m = fmaxf(m, xs[a]);
                atomicMin(&pvb[a], xib);
                a = par[a];
            }
            m = fmaxf(m, xs[0]);
        }
        mcm[c] = m;
    }
    __syncthreads();

    // BCE terms + probs store.
    float4 y4 = reinterpret_cast<const float4*>(y)[t];
    float yv[4] = {y4.x, y4.y, y4.z, y4.w};
    float acc = 0.0f;
    #pragma unroll
    for (int c = 0; c < 4; ++c) {
        const int i = base + c;
        const float pv = __int_as_float(pvb[i]);
        const float hs = (1.0f - yv[c]) * mcm[c] + pv * yv[c];
        const float lp  = fmaxf(logf(hs), -100.0f);
        const float l1p = fmaxf(log1pf(-hs), -100.0f);
        acc += yv[c] * lp + (1.0f - yv[c]) * l1p;
        out[1 + (size_t)b * CC + i] = xv[c];  // probs
    }

    #pragma unroll
    for (int off = 32; off > 0; off >>= 1) acc += __shfl_down(acc, off);
    if ((t & 63) == 0) redsum[t >> 6] = acc;
    __syncthreads();
    if (t == 0) partial[b] = (redsum[0] + redsum[1]) + (redsum[2] + redsum[3]);

    __threadfence();
    grid.sync();

    // ---------------- Phase 3: deterministic final reduction ----------------
    if (b == 0 && t < 64) {
        float v = partial[t];
        #pragma unroll
        for (int off = 32; off > 0; off >>= 1) v += __shfl_down(v, off);
        if (t == 0) out[0] = -v / (float)(BB * CC);
    }
}

extern "C" void kernel_launch(void* const* d_in, const int* in_sizes, int n_in,
                              void* d_out, int out_size, void* d_ws, size_t ws_size,
                              hipStream_t stream) {
    const float* H = (const float*)d_in[0];  // (B, C) logits
    const float* Y = (const float*)d_in[1];  // (B, C) labels
    const float* R = (const float*)d_in[2];  // (C, C) ancestry

    float* out     = (float*)d_out;          // [loss(1), probs(B*C)]
    int*   parent  = (int*)d_ws;             // C ints
    float* partial = (float*)d_ws + CC;      // B floats

    void* args[] = {(void*)&H, (void*)&Y, (void*)&R, (void*)&out,
                    (void*)&parent, (void*)&partial};
    hipLaunchCooperativeKernel((void*)k_fused, dim3(GRID), dim3(BLK), args, 0, stream);
}

// Round 3
// 19.187 us; speedup vs baseline: 3.0395x; 3.0395x over previous
//
#include <hip/hip_runtime.h>
#include <cstdint>
#include <cstddef>

#define BB 64
#define CC 1024

// Kernel 1: parent[i] = max{ j < i : R[i,j] != 0 }. Ancestor chains are strictly
// decreasing by construction, so the largest proper ancestor is the parent.
// One wave per row, float4 loads (<=4 iterations of 1 KB per wave).
// Block 0 / thread 0 also zeroes the completion counter used by k_main
// (stream order guarantees this happens before k_main starts).
__global__ __launch_bounds__(256) void k_parent(const float* __restrict__ R,
                                                int* __restrict__ parent,
                                                int* __restrict__ counter) {
    if (blockIdx.x == 0 && threadIdx.x == 0) *counter = 0;

    const int w = threadIdx.x >> 6;
    const int lane = threadIdx.x & 63;
    const int i = (blockIdx.x << 2) | w;  // row, 0..1023

    const float4* row4 = reinterpret_cast<const float4*>(R + (size_t)i * CC);
    int best = -1;
    const int nseg = (i + 255) >> 8;  // 256-float segments covering j < i
    for (int s = 0; s < nseg; ++s) {
        float4 v = row4[(s << 6) + lane];
        const int j0 = (s << 8) + (lane << 2);
        if (j0 + 0 < i && v.x != 0.0f) best = j0 + 0;
        if (j0 + 1 < i && v.y != 0.0f) best = j0 + 1;
        if (j0 + 2 < i && v.z != 0.0f) best = j0 + 2;
        if (j0 + 3 < i && v.w != 0.0f) best = j0 + 3;
    }
    #pragma unroll
    for (int off = 32; off > 0; off >>= 1) {
        int o = __shfl_down(best, off);
        best = best > o ? best : o;
    }
    if (lane == 0) parent[i] = best < 0 ? 0 : best;
}

// Kernel 2: one block per batch b.
//   x = sigmoid(h); probs = x (argmax of paths is provably root 0; R[:,0]==1);
//   mcm via ancestor-chain max walk; pv via ancestor-chain scatter with
//   deterministic integer atomicMin on LDS; per-batch partial BCE sum;
//   last block to finish does the (fixed-order, deterministic) final sum.
__global__ __launch_bounds__(256) void k_main(const float* __restrict__ H,
                                              const float* __restrict__ Y,
                                              const int* __restrict__ parent,
                                              float* __restrict__ out,
                                              float* __restrict__ partial,
                                              int* __restrict__ counter) {
    __shared__ float xs[CC];
    __shared__ int   pvb[CC];
    __shared__ int   par[CC];
    __shared__ float redsum[4];
    __shared__ int   lastflag;

    const int b = blockIdx.x;
    const int t = threadIdx.x;

    const float* h = H + (size_t)b * CC;
    const float* y = Y + (size_t)b * CC;

    // load h (float4), sigmoid, init LDS
    float4 h4 = reinterpret_cast<const float4*>(h)[t];
    float xv[4];
    xv[0] = 1.0f / (1.0f + expf(-h4.x));
    xv[1] = 1.0f / (1.0f + expf(-h4.y));
    xv[2] = 1.0f / (1.0f + expf(-h4.z));
    xv[3] = 1.0f / (1.0f + expf(-h4.w));

    int4 p4 = reinterpret_cast<const int4*>(parent)[t];
    const int base = 4 * t;
    par[base + 0] = p4.x;
    par[base + 1] = p4.y;
    par[base + 2] = p4.z;
    par[base + 3] = p4.w;
    #pragma unroll
    for (int c = 0; c < 4; ++c) {
        xs[base + c]  = xv[c];
        pvb[base + c] = __float_as_int(xv[c]);
    }
    __syncthreads();

    // pv for root = min over ALL x (block reduction, avoids 1024-way atomics on pvb[0])
    float lm = fminf(fminf(xv[0], xv[1]), fminf(xv[2], xv[3]));
    #pragma unroll
    for (int off = 32; off > 0; off >>= 1) lm = fminf(lm, __shfl_down(lm, off));
    if ((t & 63) == 0) atomicMin(&pvb[0], __float_as_int(lm));

    // ancestor-chain walks: mcm (register max) + pv scatter (LDS atomicMin)
    float mcm[4];
    #pragma unroll
    for (int c = 0; c < 4; ++c) {
        const int i = base + c;
        float m = xv[c];
        if (i != 0) {
            const int xib = __float_as_int(xv[c]);
            int a = par[i];
            while (a != 0) {
                m = fmaxf(m, xs[a]);
                atomicMin(&pvb[a], xib);
                a = par[a];
            }
            m = fmaxf(m, xs[0]);
        }
        mcm[c] = m;
    }
    __syncthreads();

    // BCE terms + probs store
    float4 y4 = reinterpret_cast<const float4*>(y)[t];
    float yv[4] = {y4.x, y4.y, y4.z, y4.w};
    float acc = 0.0f;
    #pragma unroll
    for (int c = 0; c < 4; ++c) {
        const int i = base + c;
        const float pv = __int_as_float(pvb[i]);
        const float hs = (1.0f - yv[c]) * mcm[c] + pv * yv[c];
        const float lp  = fmaxf(logf(hs), -100.0f);
        const float l1p = fmaxf(log1pf(-hs), -100.0f);
        acc += yv[c] * lp + (1.0f - yv[c]) * l1p;
        out[1 + (size_t)b * CC + i] = xv[c];  // probs
    }

    // deterministic block reduction of the partial loss
    #pragma unroll
    for (int off = 32; off > 0; off >>= 1) acc += __shfl_down(acc, off);
    if ((t & 63) == 0) redsum[t >> 6] = acc;
    __syncthreads();
    if (t == 0) {
        partial[b] = (redsum[0] + redsum[1]) + (redsum[2] + redsum[3]);
        __threadfence();                       // release partial[b]
        lastflag = (atomicAdd(counter, 1) == BB - 1);
    }
    __syncthreads();

    // last block: fixed-order final reduction (deterministic)
    if (lastflag && t < 64) {
        float v = ((volatile float*)partial)[t];  // bypass L1; others' fences done
        #pragma unroll
        for (int off = 32; off > 0; off >>= 1) v += __shfl_down(v, off);
        if (t == 0) out[0] = -v / (float)(BB * CC);
    }
}

extern "C" void kernel_launch(void* const* d_in, const int* in_sizes, int n_in,
                              void* d_out, int out_size, void* d_ws, size_t ws_size,
                              hipStream_t stream) {
    const float* H = (const float*)d_in[0];  // (B, C) logits
    const float* Y = (const float*)d_in[1];  // (B, C) labels
    const float* R = (const float*)d_in[2];  // (C, C) ancestry

    float* out     = (float*)d_out;          // [loss(1), probs(B*C)]
    int*   parent  = (int*)d_ws;             // C ints
    float* partial = (float*)d_ws + CC;      // B floats
    int*   counter = (int*)d_ws + CC + BB;   // 1 int

    k_parent<<<CC / 4, 256, 0, stream>>>(R, parent, counter);
    k_main<<<BB, 256, 0, stream>>>(H, Y, parent, out, partial, counter);
}